// Round 1
// baseline (107.519 us; speedup 1.0000x reference)
//
#include <hip/hip_runtime.h>
#include <math.h>

// ---------------------------------------------------------------------------
// HQNN: per-row fused dense+tanh+4-qubit-circuit, 3 layers.
// One thread per batch row; 16-amp complex state fully in registers.
// Entangler sin/cos (batch-constant) precomputed into d_ws by setup kernel.
// ---------------------------------------------------------------------------

__device__ __forceinline__ float fast_tanh(float x) {
    // tanh(x) = 1 - 2/(e^{2x}+1); robust at +/-inf, accuracy ~1e-6 rel.
    float u = __expf(2.0f * x);
    return 1.0f - 2.0f * __builtin_amdgcn_rcpf(u + 1.0f);
}

// RX(theta) on wire w: c = cos(t/2), s = sin(t/2) (gate factor is -i*s).
__device__ __forceinline__ void apply_rx(float2 st[16], int w, float c, float s) {
    const int bit = 1 << w;
#pragma unroll
    for (int b = 0; b < 16; ++b) {
        if (!(b & bit)) {
            float2 a0 = st[b];
            float2 a1 = st[b | bit];
            // new0 = c*a0 + (-i s)*a1 ; new1 = (-i s)*a0 + c*a1
            st[b].x       = fmaf(c, a0.x,  s * a1.y);
            st[b].y       = fmaf(c, a0.y, -s * a1.x);
            st[b | bit].x = fmaf(c, a1.x,  s * a0.y);
            st[b | bit].y = fmaf(c, a1.y, -s * a0.x);
        }
    }
}

// CNOT(control, target): swap amplitudes where control bit = 1 (register renames)
__device__ __forceinline__ void apply_cnot(float2 st[16], int c, int t) {
    const int cb = 1 << c, tb = 1 << t;
#pragma unroll
    for (int b = 0; b < 16; ++b) {
        if ((b & cb) && !(b & tb)) {
            float2 tmp = st[b];
            st[b] = st[b | tb];
            st[b | tb] = tmp;
        }
    }
}

// One 4-qubit circuit: RX embedding with angles h[4], then 2 entangler layers
// (RX with precomputed c/s + CNOT ring), then Z expvals back into h[4].
// scL points to this layer's 16 floats: [entlayer][wire][{cos,sin}].
__device__ __forceinline__ void qnn(float h[4], const float* __restrict__ scL) {
    float2 st[16];
#pragma unroll
    for (int b = 0; b < 16; ++b) st[b] = make_float2(0.0f, 0.0f);
    st[0] = make_float2(1.0f, 0.0f);

    // AngleEmbedding: RX(h[w]) on wire w (|h|<=1 so half-angle tiny; native sin/cos fine)
#pragma unroll
    for (int w = 0; w < 4; ++w) {
        float t = 0.5f * h[w];
        apply_rx(st, w, __cosf(t), __sinf(t));
    }

    // BasicEntanglerLayers
#pragma unroll
    for (int l = 0; l < 2; ++l) {
#pragma unroll
        for (int w = 0; w < 4; ++w)
            apply_rx(st, w, scL[(l * 4 + w) * 2 + 0], scL[(l * 4 + w) * 2 + 1]);
#pragma unroll
        for (int w = 0; w < 4; ++w)
            apply_cnot(st, w, (w + 1) & 3);
    }

    // Z expvals
    float pr[16];
#pragma unroll
    for (int b = 0; b < 16; ++b)
        pr[b] = fmaf(st[b].x, st[b].x, st[b].y * st[b].y);

    float total = 0.0f;
#pragma unroll
    for (int b = 0; b < 16; ++b) total += pr[b];
#pragma unroll
    for (int w = 0; w < 4; ++w) {
        float s1 = 0.0f;                 // sum of probs where bit w is set
#pragma unroll
        for (int b = 0; b < 16; ++b)
            if ((b >> w) & 1) s1 += pr[b];
        h[w] = fmaf(-2.0f, s1, total);   // (total - s1) - s1
    }
}

__device__ __forceinline__ void dense4(float h[4], const float* __restrict__ W,
                                       const float* __restrict__ b) {
    float g[4];
#pragma unroll
    for (int j = 0; j < 4; ++j) {
        float acc = b[j];
#pragma unroll
        for (int k = 0; k < 4; ++k) acc = fmaf(h[k], W[k * 4 + j], acc);
        g[j] = fast_tanh(acc);
    }
#pragma unroll
    for (int j = 0; j < 4; ++j) h[j] = g[j];
}

// Precompute cos/sin of theta/2 for the 24 entangler angles (batch-constant).
__global__ void setup_sc(const float* __restrict__ theta, float* __restrict__ sc) {
    int tid = threadIdx.x;
    if (tid < 24) {
        float t = 0.5f * theta[tid];
        sc[2 * tid + 0] = cosf(t);
        sc[2 * tid + 1] = sinf(t);
    }
}

__global__ __launch_bounds__(256)
void hqnn_kernel(const float4* __restrict__ x4,
                 const float* __restrict__ sc,
                 const float* __restrict__ W0, const float* __restrict__ b0,
                 const float* __restrict__ W1, const float* __restrict__ b1,
                 const float* __restrict__ W2, const float* __restrict__ b2,
                 float4* __restrict__ out, int B) {
    int i = blockIdx.x * blockDim.x + threadIdx.x;
    if (i >= B) return;

    // Load the 16-float input row as 4x float4.
    float xr[16];
    float4 v0 = x4[i * 4 + 0];
    float4 v1 = x4[i * 4 + 1];
    float4 v2 = x4[i * 4 + 2];
    float4 v3 = x4[i * 4 + 3];
    xr[0] = v0.x; xr[1] = v0.y; xr[2]  = v0.z; xr[3]  = v0.w;
    xr[4] = v1.x; xr[5] = v1.y; xr[6]  = v1.z; xr[7]  = v1.w;
    xr[8] = v2.x; xr[9] = v2.y; xr[10] = v2.z; xr[11] = v2.w;
    xr[12] = v3.x; xr[13] = v3.y; xr[14] = v3.z; xr[15] = v3.w;

    float h[4];
    // Layer 0 dense: 16 -> 4, weights are (16,4) row-major; uniform scalar loads.
#pragma unroll
    for (int j = 0; j < 4; ++j) {
        float acc = b0[j];
#pragma unroll
        for (int k = 0; k < 16; ++k) acc = fmaf(xr[k], W0[k * 4 + j], acc);
        h[j] = fast_tanh(acc);
    }
    qnn(h, sc + 0 * 16);

    dense4(h, W1, b1);
    qnn(h, sc + 1 * 16);

    dense4(h, W2, b2);
    qnn(h, sc + 2 * 16);

    out[i] = make_float4(h[0], h[1], h[2], h[3]);
}

extern "C" void kernel_launch(void* const* d_in, const int* in_sizes, int n_in,
                              void* d_out, int out_size, void* d_ws, size_t ws_size,
                              hipStream_t stream) {
    const float* x  = (const float*)d_in[0];
    const float* th = (const float*)d_in[1];   // (3,2,4) = 24 floats
    const float* W0 = (const float*)d_in[2];
    const float* b0 = (const float*)d_in[3];
    const float* W1 = (const float*)d_in[4];
    const float* b1 = (const float*)d_in[5];
    const float* W2 = (const float*)d_in[6];
    const float* b2 = (const float*)d_in[7];
    float* out = (float*)d_out;
    float* sc  = (float*)d_ws;                 // 48 floats

    int B = in_sizes[0] / 16;

    hipLaunchKernelGGL(setup_sc, dim3(1), dim3(32), 0, stream, th, sc);

    int block = 256;
    int grid = (B + block - 1) / block;
    hipLaunchKernelGGL(hqnn_kernel, dim3(grid), dim3(block), 0, stream,
                       (const float4*)x, sc, W0, b0, W1, b1, W2, b2,
                       (float4*)out, B);
}